// Round 1
// baseline (1598.532 us; speedup 1.0000x reference)
//
#include <hip/hip_runtime.h>
#include <cstddef>
#include <cstdint>

// Problem constants (from reference): EMBED=1024, HEADS=16, GQA=4, KV_HEADS=4,
// HEAD_DIM=64, KV_EMBED=256, EPS=1e-3, B=2, T=1024.
#define TSEQ 1024

// Workspace layout (floats):
//  XQ: 2048 x 1024   (2M)
//  XK: 2048 x 256    (0.5M)
//  XV: 2048 x 256    (0.5M)
//  XO: 2048 x 1024   (2M)
//  P : 32 x 1024x1024 (33.554432M) -- probs, overwritten in place by phi
static constexpr size_t OFF_XQ = 0;
static constexpr size_t OFF_XK = (size_t)2 * 1024 * 1024;
static constexpr size_t OFF_XV = OFF_XK + (size_t)512 * 1024;
static constexpr size_t OFF_XO = OFF_XV + (size_t)512 * 1024;
static constexpr size_t OFF_P  = OFF_XO + (size_t)2 * 1024 * 1024;

// ---------------------------------------------------------------------------
// Generic fp32 GEMM:  C[M,N] = A[M,K] @ W[N,K]^T + bias[N]
// Tiles 64x64x16, 256 threads, 4x4 per thread. All dims multiples of 64/16.
// ---------------------------------------------------------------------------
__global__ __launch_bounds__(256) void gemm_nt_bias_k(
    const float* __restrict__ A, const float* __restrict__ W,
    const float* __restrict__ bias, float* __restrict__ C,
    int K, int lda, int ldw, int ldc)
{
  __shared__ float As[16][64];
  __shared__ float Bs[16][64];
  const int bm = blockIdx.y << 6;
  const int bn = blockIdx.x << 6;
  const int tid = threadIdx.x;
  const int tr = (tid >> 4) << 2;   // 0..60
  const int tc = (tid & 15) << 2;   // 0..60
  const int lr = tid >> 2;          // 0..63
  const int lc = (tid & 3) << 2;    // 0,4,8,12

  float acc[4][4] = {};
  for (int k0 = 0; k0 < K; k0 += 16) {
    float4 av = *(const float4*)(A + (size_t)(bm + lr) * lda + (k0 + lc));
    float4 wv = *(const float4*)(W + (size_t)(bn + lr) * ldw + (k0 + lc));
    As[lc + 0][lr] = av.x; As[lc + 1][lr] = av.y;
    As[lc + 2][lr] = av.z; As[lc + 3][lr] = av.w;
    Bs[lc + 0][lr] = wv.x; Bs[lc + 1][lr] = wv.y;
    Bs[lc + 2][lr] = wv.z; Bs[lc + 3][lr] = wv.w;
    __syncthreads();
#pragma unroll
    for (int k = 0; k < 16; ++k) {
      float a[4], b[4];
#pragma unroll
      for (int i = 0; i < 4; ++i) a[i] = As[k][tr + i];
#pragma unroll
      for (int j = 0; j < 4; ++j) b[j] = Bs[k][tc + j];
#pragma unroll
      for (int i = 0; i < 4; ++i)
#pragma unroll
        for (int j = 0; j < 4; ++j)
          acc[i][j] = fmaf(a[i], b[j], acc[i][j]);
    }
    __syncthreads();
  }
#pragma unroll
  for (int i = 0; i < 4; ++i) {
    float4 v;
    v.x = acc[i][0] + bias[bn + tc + 0];
    v.y = acc[i][1] + bias[bn + tc + 1];
    v.z = acc[i][2] + bias[bn + tc + 2];
    v.w = acc[i][3] + bias[bn + tc + 3];
    *(float4*)(C + (size_t)(bm + tr + i) * ldc + (bn + tc)) = v;
  }
}

// ---------------------------------------------------------------------------
// Scores: per z=(b*16+g*4+h): P[z][i][j] = clip(sigmoid(Q[i]·K[j]), eps, 1-eps)
// Q rows: XQ[b, i, head*64 + c] (lda=1024); K rows: XK[b, j, h*64 + c] (ldb=256)
// ---------------------------------------------------------------------------
__global__ __launch_bounds__(256) void scores_k(
    const float* __restrict__ XQ, const float* __restrict__ XK,
    float* __restrict__ P)
{
  __shared__ float As[16][64];
  __shared__ float Bs[16][64];
  const int z = blockIdx.z;
  const int b = z >> 4;
  const int h = z & 3;
  const float* A = XQ + ((size_t)b << 20) + ((size_t)(z & 15) << 6);   // lda 1024
  const float* B = XK + (size_t)b * (TSEQ * 256) + ((size_t)h << 6);   // ldb 256
  float* C = P + ((size_t)z << 20);                                    // ldc 1024

  const int bm = blockIdx.y << 6;
  const int bn = blockIdx.x << 6;
  const int tid = threadIdx.x;
  const int tr = (tid >> 4) << 2;
  const int tc = (tid & 15) << 2;
  const int lr = tid >> 2;
  const int lc = (tid & 3) << 2;

  float acc[4][4] = {};
#pragma unroll
  for (int k0 = 0; k0 < 64; k0 += 16) {
    float4 av = *(const float4*)(A + (size_t)(bm + lr) * 1024 + (k0 + lc));
    float4 bv = *(const float4*)(B + (size_t)(bn + lr) * 256 + (k0 + lc));
    As[lc + 0][lr] = av.x; As[lc + 1][lr] = av.y;
    As[lc + 2][lr] = av.z; As[lc + 3][lr] = av.w;
    Bs[lc + 0][lr] = bv.x; Bs[lc + 1][lr] = bv.y;
    Bs[lc + 2][lr] = bv.z; Bs[lc + 3][lr] = bv.w;
    __syncthreads();
#pragma unroll
    for (int k = 0; k < 16; ++k) {
      float a[4], b4[4];
#pragma unroll
      for (int i = 0; i < 4; ++i) a[i] = As[k][tr + i];
#pragma unroll
      for (int j = 0; j < 4; ++j) b4[j] = Bs[k][tc + j];
#pragma unroll
      for (int i = 0; i < 4; ++i)
#pragma unroll
        for (int j = 0; j < 4; ++j)
          acc[i][j] = fmaf(a[i], b4[j], acc[i][j]);
    }
    __syncthreads();
  }
#pragma unroll
  for (int i = 0; i < 4; ++i) {
    float4 v;
#pragma unroll
    for (int j = 0; j < 4; ++j) {
      float p = 1.0f / (1.0f + expf(-acc[i][j]));
      p = fminf(fmaxf(p, 0.001f), 0.999f);
      ((float*)&v)[j] = p;
    }
    *(float4*)(C + (size_t)(bm + tr + i) * 1024 + (bn + tc)) = v;
  }
}

// ---------------------------------------------------------------------------
// Monotonic recurrence, in place over P (probs -> phi).
// One block per (b,g,h); 1024 threads, thread j owns column j.
// phi[0,:] = onehot(0);  phi[i,j] = (1-p[i,j-1])*phi[i,j-1] + p[i-1,j]*phi[i-1,j]
// Row recurrence solved as block-wide scan of affine maps (A,b):
//   combine(lo, hi) = (A_lo*A_hi, b_lo*A_hi + b_hi)
// ---------------------------------------------------------------------------
__global__ __launch_bounds__(1024) void mono_rec_k(float* __restrict__ P)
{
  const int z = blockIdx.x;
  float* Pz = P + ((size_t)z << 20);
  const int j = threadIdx.x;
  const int lane = j & 63;
  const int wave = j >> 6;
  __shared__ float aggA[2][16];
  __shared__ float aggB[2][16];

  // Row 0
  float p_prev = Pz[j];
  float phi = (j == 0) ? 1.0f : 0.0f;
  Pz[j] = phi;

  // Prefetch row 1
  float p_nx = Pz[TSEQ + j];
  float pl_nx = 0.0f;
  if (lane == 0 && j > 0) pl_nx = Pz[TSEQ + j - 1];

  for (int i = 1; i < TSEQ; ++i) {
    const float p_cur = p_nx;
    const float p_leftb = pl_nx;
    if (i + 1 < TSEQ) {
      const size_t row = (size_t)(i + 1) << 10;
      p_nx = Pz[row + j];
      if (lane == 0 && j > 0) pl_nx = Pz[row + j - 1];
    }

    // element (A_j, b_j): b_j = phi[i-1,j]*p[i-1,j]; A_j = 1 - p[i,j-1] (0 at j=0)
    const float a = phi * p_prev;
    float pl = __shfl_up(p_cur, 1);
    if (lane == 0) pl = p_leftb;
    float sA = (j == 0) ? 0.0f : (1.0f - pl);
    float sB = a;

    // intra-wave inclusive scan (affine composition)
#pragma unroll
    for (int off = 1; off < 64; off <<= 1) {
      float uA = __shfl_up(sA, off);
      float uB = __shfl_up(sB, off);
      if (lane >= off) { sB = fmaf(uB, sA, sB); sA = uA * sA; }
    }

    const int buf = i & 1;  // double-buffered aggregates: 1 barrier/iter is race-free
    if (lane == 63) { aggA[buf][wave] = sA; aggB[buf][wave] = sB; }
    __syncthreads();

    // every wave redundantly scans the 16 wave aggregates, takes prefix (wave-1)
    float pB = 0.0f;
    {
      float wA = 1.0f, wB = 0.0f;
      if (lane < 16) { wA = aggA[buf][lane]; wB = aggB[buf][lane]; }
#pragma unroll
      for (int off = 1; off < 16; off <<= 1) {
        float uA = __shfl_up(wA, off);
        float uB = __shfl_up(wB, off);
        if (lane >= off) { wB = fmaf(uB, wA, wB); wA = uA * wA; }
      }
      if (wave > 0) pB = __shfl(wB, wave - 1);
    }
    // phi_j = b-component of (prefix ∘ local); A-chain contains A_0=0 so b is exact phi
    const float phi_new = fmaf(pB, sA, sB);
    Pz[((size_t)i << 10) + j] = phi_new;

    phi = phi_new;
    p_prev = p_cur;
  }
}

// ---------------------------------------------------------------------------
// PV: per z: XO_sub[i,c] = sum_j phi[i,j] * V[j,c]   (NN GEMM, M=1024,N=64,K=1024)
// ---------------------------------------------------------------------------
__global__ __launch_bounds__(256) void pv_k(
    const float* __restrict__ P, const float* __restrict__ XV,
    float* __restrict__ XO)
{
  __shared__ float As[16][64];
  __shared__ float Bs[16][64];
  const int z = blockIdx.z;
  const int b = z >> 4;
  const int h = z & 3;
  const float* A = P + ((size_t)z << 20);                               // lda 1024
  const float* B = XV + (size_t)b * (TSEQ * 256) + ((size_t)h << 6);    // ldb 256
  float* C = XO + ((size_t)b << 20) + ((size_t)(z & 15) << 6);          // ldc 1024

  const int bm = blockIdx.y << 6;
  const int tid = threadIdx.x;
  const int tr = (tid >> 4) << 2;
  const int tc = (tid & 15) << 2;
  const int lr = tid >> 2;          // A-tile loader
  const int lc = (tid & 3) << 2;
  const int br = tid >> 4;          // B-tile loader: 16 rows x 64 cols
  const int bc = (tid & 15) << 2;

  float acc[4][4] = {};
  for (int k0 = 0; k0 < 1024; k0 += 16) {
    float4 av = *(const float4*)(A + (size_t)(bm + lr) * 1024 + (k0 + lc));
    float4 bv = *(const float4*)(B + (size_t)(k0 + br) * 256 + bc);
    As[lc + 0][lr] = av.x; As[lc + 1][lr] = av.y;
    As[lc + 2][lr] = av.z; As[lc + 3][lr] = av.w;
    Bs[br][bc + 0] = bv.x; Bs[br][bc + 1] = bv.y;
    Bs[br][bc + 2] = bv.z; Bs[br][bc + 3] = bv.w;
    __syncthreads();
#pragma unroll
    for (int k = 0; k < 16; ++k) {
      float a[4], b4[4];
#pragma unroll
      for (int i = 0; i < 4; ++i) a[i] = As[k][tr + i];
#pragma unroll
      for (int jj = 0; jj < 4; ++jj) b4[jj] = Bs[k][tc + jj];
#pragma unroll
      for (int i = 0; i < 4; ++i)
#pragma unroll
        for (int jj = 0; jj < 4; ++jj)
          acc[i][jj] = fmaf(a[i], b4[jj], acc[i][jj]);
    }
    __syncthreads();
  }
#pragma unroll
  for (int i = 0; i < 4; ++i) {
    float4 v;
    v.x = acc[i][0]; v.y = acc[i][1]; v.z = acc[i][2]; v.w = acc[i][3];
    *(float4*)(C + (size_t)(bm + tr + i) * 1024 + tc) = v;
  }
}

// ---------------------------------------------------------------------------
extern "C" void kernel_launch(void* const* d_in, const int* in_sizes, int n_in,
                              void* d_out, int out_size, void* d_ws, size_t ws_size,
                              hipStream_t stream)
{
  const float* query = (const float*)d_in[0];
  const float* key   = (const float*)d_in[1];
  const float* value = (const float*)d_in[2];
  const float* ipw   = (const float*)d_in[3];   // (1536,1024)
  const float* ipb   = (const float*)d_in[4];   // (1536,)
  const float* opw   = (const float*)d_in[5];   // (1024,1024)
  const float* opb   = (const float*)d_in[6];   // (1024,)
  float* out = (float*)d_out;
  float* ws  = (float*)d_ws;

  float* XQ = ws + OFF_XQ;
  float* XK = ws + OFF_XK;
  float* XV = ws + OFF_XV;
  float* XO = ws + OFF_XO;
  float* P  = ws + OFF_P;

  dim3 blk(256);

  // in-projections: M=2048 rows
  gemm_nt_bias_k<<<dim3(16, 32), blk, 0, stream>>>(
      query, ipw, ipb, XQ, 1024, 1024, 1024, 1024);
  gemm_nt_bias_k<<<dim3(4, 32), blk, 0, stream>>>(
      key, ipw + (size_t)1024 * 1024, ipb + 1024, XK, 1024, 1024, 1024, 256);
  gemm_nt_bias_k<<<dim3(4, 32), blk, 0, stream>>>(
      value, ipw + (size_t)1280 * 1024, ipb + 1280, XV, 1024, 1024, 1024, 256);

  // scores + sigmoid + clip -> P
  scores_k<<<dim3(16, 16, 32), blk, 0, stream>>>(XQ, XK, P);

  // monotonic recurrence in place
  mono_rec_k<<<dim3(32), dim3(1024), 0, stream>>>(P);

  // phi @ V -> XO
  pv_k<<<dim3(1, 16, 32), blk, 0, stream>>>(P, XV, XO);

  // out-projection
  gemm_nt_bias_k<<<dim3(16, 32), blk, 0, stream>>>(
      XO, opw, opb, out, 1024, 1024, 1024, 1024);
}

// Round 2
// 1030.201 us; speedup vs baseline: 1.5517x; 1.5517x over previous
//
#include <hip/hip_runtime.h>
#include <cstddef>
#include <cstdint>

// Problem constants (from reference): EMBED=1024, HEADS=16, GQA=4, KV_HEADS=4,
// HEAD_DIM=64, KV_EMBED=256, EPS=1e-3, B=2, T=1024.
#define TSEQ 1024

// Workspace layout (floats):
//  XQ: 2048 x 1024   (2M)
//  XK: 2048 x 256    (0.5M)
//  XV: 2048 x 256    (0.5M)
//  XO: 2048 x 1024   (2M)
//  P : 32 x 1024x1024 (33.554432M) -- probs, overwritten in place by phi
static constexpr size_t OFF_XQ = 0;
static constexpr size_t OFF_XK = (size_t)2 * 1024 * 1024;
static constexpr size_t OFF_XV = OFF_XK + (size_t)512 * 1024;
static constexpr size_t OFF_XO = OFF_XV + (size_t)512 * 1024;
static constexpr size_t OFF_P  = OFF_XO + (size_t)2 * 1024 * 1024;

// ---------------------------------------------------------------------------
// Generic fp32 GEMM:  C[M,N] = A[M,K] @ W[N,K]^T + bias[N]
// Tiles 64x64x16, 256 threads, 4x4 per thread. All dims multiples of 64/16.
// ---------------------------------------------------------------------------
__global__ __launch_bounds__(256) void gemm_nt_bias_k(
    const float* __restrict__ A, const float* __restrict__ W,
    const float* __restrict__ bias, float* __restrict__ C,
    int K, int lda, int ldw, int ldc)
{
  __shared__ float As[16][64];
  __shared__ float Bs[16][64];
  const int bm = blockIdx.y << 6;
  const int bn = blockIdx.x << 6;
  const int tid = threadIdx.x;
  const int tr = (tid >> 4) << 2;   // 0..60
  const int tc = (tid & 15) << 2;   // 0..60
  const int lr = tid >> 2;          // 0..63
  const int lc = (tid & 3) << 2;    // 0,4,8,12

  float acc[4][4] = {};
  for (int k0 = 0; k0 < K; k0 += 16) {
    float4 av = *(const float4*)(A + (size_t)(bm + lr) * lda + (k0 + lc));
    float4 wv = *(const float4*)(W + (size_t)(bn + lr) * ldw + (k0 + lc));
    As[lc + 0][lr] = av.x; As[lc + 1][lr] = av.y;
    As[lc + 2][lr] = av.z; As[lc + 3][lr] = av.w;
    Bs[lc + 0][lr] = wv.x; Bs[lc + 1][lr] = wv.y;
    Bs[lc + 2][lr] = wv.z; Bs[lc + 3][lr] = wv.w;
    __syncthreads();
#pragma unroll
    for (int k = 0; k < 16; ++k) {
      float a[4], b[4];
#pragma unroll
      for (int i = 0; i < 4; ++i) a[i] = As[k][tr + i];
#pragma unroll
      for (int j = 0; j < 4; ++j) b[j] = Bs[k][tc + j];
#pragma unroll
      for (int i = 0; i < 4; ++i)
#pragma unroll
        for (int j = 0; j < 4; ++j)
          acc[i][j] = fmaf(a[i], b[j], acc[i][j]);
    }
    __syncthreads();
  }
#pragma unroll
  for (int i = 0; i < 4; ++i) {
    float4 v;
    v.x = acc[i][0] + bias[bn + tc + 0];
    v.y = acc[i][1] + bias[bn + tc + 1];
    v.z = acc[i][2] + bias[bn + tc + 2];
    v.w = acc[i][3] + bias[bn + tc + 3];
    *(float4*)(C + (size_t)(bm + tr + i) * ldc + (bn + tc)) = v;
  }
}

// ---------------------------------------------------------------------------
// Scores: per z=(b*16+g*4+h): P[z][i][j] = clip(sigmoid(Q[i]·K[j]), eps, 1-eps)
// Q rows: XQ[b, i, head*64 + c] (lda=1024); K rows: XK[b, j, h*64 + c] (ldb=256)
// ---------------------------------------------------------------------------
__global__ __launch_bounds__(256) void scores_k(
    const float* __restrict__ XQ, const float* __restrict__ XK,
    float* __restrict__ P)
{
  __shared__ float As[16][64];
  __shared__ float Bs[16][64];
  const int z = blockIdx.z;
  const int b = z >> 4;
  const int h = z & 3;
  const float* A = XQ + ((size_t)b << 20) + ((size_t)(z & 15) << 6);   // lda 1024
  const float* B = XK + (size_t)b * (TSEQ * 256) + ((size_t)h << 6);   // ldb 256
  float* C = P + ((size_t)z << 20);                                    // ldc 1024

  const int bm = blockIdx.y << 6;
  const int bn = blockIdx.x << 6;
  const int tid = threadIdx.x;
  const int tr = (tid >> 4) << 2;
  const int tc = (tid & 15) << 2;
  const int lr = tid >> 2;
  const int lc = (tid & 3) << 2;

  float acc[4][4] = {};
#pragma unroll
  for (int k0 = 0; k0 < 64; k0 += 16) {
    float4 av = *(const float4*)(A + (size_t)(bm + lr) * 1024 + (k0 + lc));
    float4 bv = *(const float4*)(B + (size_t)(bn + lr) * 256 + (k0 + lc));
    As[lc + 0][lr] = av.x; As[lc + 1][lr] = av.y;
    As[lc + 2][lr] = av.z; As[lc + 3][lr] = av.w;
    Bs[lc + 0][lr] = bv.x; Bs[lc + 1][lr] = bv.y;
    Bs[lc + 2][lr] = bv.z; Bs[lc + 3][lr] = bv.w;
    __syncthreads();
#pragma unroll
    for (int k = 0; k < 16; ++k) {
      float a[4], b4[4];
#pragma unroll
      for (int i = 0; i < 4; ++i) a[i] = As[k][tr + i];
#pragma unroll
      for (int j = 0; j < 4; ++j) b4[j] = Bs[k][tc + j];
#pragma unroll
      for (int i = 0; i < 4; ++i)
#pragma unroll
        for (int j = 0; j < 4; ++j)
          acc[i][j] = fmaf(a[i], b4[j], acc[i][j]);
    }
    __syncthreads();
  }
#pragma unroll
  for (int i = 0; i < 4; ++i) {
    float4 v;
#pragma unroll
    for (int j = 0; j < 4; ++j) {
      float p = 1.0f / (1.0f + expf(-acc[i][j]));
      p = fminf(fmaxf(p, 0.001f), 0.999f);
      ((float*)&v)[j] = p;
    }
    *(float4*)(C + (size_t)(bm + tr + i) * 1024 + (bn + tc)) = v;
  }
}

// ---------------------------------------------------------------------------
// Monotonic recurrence, in place over P (probs -> phi).
// ONE WAVE (64 threads) per z. Lane t owns columns [16t, 16t+16). No barriers.
// phi[0,:] = onehot(0);  phi[i,j] = (1-p[i,j-1])*phi[i,j-1] + p[i-1,j]*phi[i-1,j]
// Row solved as affine scan: elem_j = (A_j, b_j), A_j = 1-p[i,j-1] (0 at j=0),
// b_j = phi[i-1,j]*p[i-1,j]; combine(lo,hi) = (A_lo*A_hi, b_lo*A_hi + b_hi).
// Per row: 16-step in-register local prefix -> 6-step wave shuffle scan of
// lane totals -> apply exclusive prefix. State: b[] carries phi*p across rows
// (so no separate p_prev). 3 rotating p-row buffers, i-loop unrolled x3, so
// the distance-2 prefetch needs no register moves.
// ---------------------------------------------------------------------------
__global__ __launch_bounds__(64) void mono_rec_k(float* __restrict__ P)
{
  const int z = blockIdx.x;
  float* __restrict__ Pz = P + ((size_t)z << 20);
  const int t = threadIdx.x;     // lane 0..63
  const int col0 = t << 4;       // first owned column

  float b[16];                   // b_c = phi[i-1,c]*p[i-1,c] for next row
  float p0[16], p1[16], p2[16];  // rotating p-row buffers

  // --- row 0: phi = onehot(0); b = phi0 * p_row0 (only col 0 nonzero) ---
  const float p00 = Pz[0];       // read BEFORE overwriting row 0 in place
  {
    float4 z4 = make_float4(0.f, 0.f, 0.f, 0.f);
    float4 v0 = z4;
    if (t == 0) v0.x = 1.0f;
    *(float4*)(Pz + col0 + 0)  = v0;
    *(float4*)(Pz + col0 + 4)  = z4;
    *(float4*)(Pz + col0 + 8)  = z4;
    *(float4*)(Pz + col0 + 12) = z4;
  }
#pragma unroll
  for (int c = 0; c < 16; ++c) b[c] = 0.0f;
  if (t == 0) b[0] = p00;

  // preload rows 1 and 2
#pragma unroll
  for (int q = 0; q < 4; ++q)
    *(float4*)&p0[4 * q] = *(const float4*)(Pz + ((size_t)1 << 10) + col0 + 4 * q);
#pragma unroll
  for (int q = 0; q < 4; ++q)
    *(float4*)&p1[4 * q] = *(const float4*)(Pz + ((size_t)2 << 10) + col0 + 4 * q);

  auto step = [&](int i, float (&pu)[16], float (&pw)[16]) {
    // prefetch row i+2 (clamped; clamped loads are never consumed)
    const size_t rowpf = (size_t)((i + 2 < TSEQ) ? (i + 2) : (TSEQ - 1)) << 10;
#pragma unroll
    for (int q = 0; q < 4; ++q)
      *(float4*)&pw[4 * q] = *(const float4*)(Pz + rowpf + col0 + 4 * q);

    // A_c = 1 - p[i, c-1]; boundary from left lane; global col 0 -> A = 0
    const float pl = __shfl_up(pu[15], 1);
    const float A0 = (t == 0) ? 0.0f : (1.0f - pl);

    // local inclusive affine prefix over own 16 columns
    float SA[16], SB[16];
    SA[0] = A0;
    SB[0] = b[0];
#pragma unroll
    for (int c = 1; c < 16; ++c) {
      const float Ac = 1.0f - pu[c - 1];
      SA[c] = SA[c - 1] * Ac;
      SB[c] = fmaf(SB[c - 1], Ac, b[c]);
    }

    // wave-wide inclusive scan of lane totals (affine composition)
    float tA = SA[15], tB = SB[15];
#pragma unroll
    for (int off = 1; off < 64; off <<= 1) {
      const float uA = __shfl_up(tA, off);
      const float uB = __shfl_up(tB, off);
      if (t >= off) { tB = fmaf(uB, tA, tB); tA = uA * tA; }
    }
    // exclusive prefix B for this lane
    float pB = __shfl_up(tB, 1);
    if (t == 0) pB = 0.0f;

    // apply, store row i, and build next row's b = phi_new * p_cur
    float phin[16];
#pragma unroll
    for (int c = 0; c < 16; ++c) {
      phin[c] = fmaf(pB, SA[c], SB[c]);
      b[c] = phin[c] * pu[c];
    }
    float* rowp = Pz + ((size_t)i << 10) + col0;
#pragma unroll
    for (int q = 0; q < 4; ++q)
      *(float4*)(rowp + 4 * q) = *(float4*)&phin[4 * q];
  };

  // 1023 iterations = 341 groups of 3; buffer roles rotate (pu, prefetch tgt)
  for (int i = 1; i < TSEQ; i += 3) {
    step(i + 0, p0, p2);
    step(i + 1, p1, p0);
    step(i + 2, p2, p1);
  }
}

// ---------------------------------------------------------------------------
// PV: per z: XO_sub[i,c] = sum_j phi[i,j] * V[j,c]   (NN GEMM, M=1024,N=64,K=1024)
// ---------------------------------------------------------------------------
__global__ __launch_bounds__(256) void pv_k(
    const float* __restrict__ P, const float* __restrict__ XV,
    float* __restrict__ XO)
{
  __shared__ float As[16][64];
  __shared__ float Bs[16][64];
  const int z = blockIdx.z;
  const int b = z >> 4;
  const int h = z & 3;
  const float* A = P + ((size_t)z << 20);                               // lda 1024
  const float* B = XV + (size_t)b * (TSEQ * 256) + ((size_t)h << 6);    // ldb 256
  float* C = XO + ((size_t)b << 20) + ((size_t)(z & 15) << 6);          // ldc 1024

  const int bm = blockIdx.y << 6;
  const int tid = threadIdx.x;
  const int tr = (tid >> 4) << 2;
  const int tc = (tid & 15) << 2;
  const int lr = tid >> 2;          // A-tile loader
  const int lc = (tid & 3) << 2;
  const int br = tid >> 4;          // B-tile loader: 16 rows x 64 cols
  const int bc = (tid & 15) << 2;

  float acc[4][4] = {};
  for (int k0 = 0; k0 < 1024; k0 += 16) {
    float4 av = *(const float4*)(A + (size_t)(bm + lr) * 1024 + (k0 + lc));
    float4 bv = *(const float4*)(B + (size_t)(k0 + br) * 256 + bc);
    As[lc + 0][lr] = av.x; As[lc + 1][lr] = av.y;
    As[lc + 2][lr] = av.z; As[lc + 3][lr] = av.w;
    Bs[br][bc + 0] = bv.x; Bs[br][bc + 1] = bv.y;
    Bs[br][bc + 2] = bv.z; Bs[br][bc + 3] = bv.w;
    __syncthreads();
#pragma unroll
    for (int k = 0; k < 16; ++k) {
      float a[4], b4[4];
#pragma unroll
      for (int i = 0; i < 4; ++i) a[i] = As[k][tr + i];
#pragma unroll
      for (int jj = 0; jj < 4; ++jj) b4[jj] = Bs[k][tc + jj];
#pragma unroll
      for (int i = 0; i < 4; ++i)
#pragma unroll
        for (int jj = 0; jj < 4; ++jj)
          acc[i][jj] = fmaf(a[i], b4[jj], acc[i][jj]);
    }
    __syncthreads();
  }
#pragma unroll
  for (int i = 0; i < 4; ++i) {
    float4 v;
    v.x = acc[i][0]; v.y = acc[i][1]; v.z = acc[i][2]; v.w = acc[i][3];
    *(float4*)(C + (size_t)(bm + tr + i) * 1024 + tc) = v;
  }
}

// ---------------------------------------------------------------------------
extern "C" void kernel_launch(void* const* d_in, const int* in_sizes, int n_in,
                              void* d_out, int out_size, void* d_ws, size_t ws_size,
                              hipStream_t stream)
{
  const float* query = (const float*)d_in[0];
  const float* key   = (const float*)d_in[1];
  const float* value = (const float*)d_in[2];
  const float* ipw   = (const float*)d_in[3];   // (1536,1024)
  const float* ipb   = (const float*)d_in[4];   // (1536,)
  const float* opw   = (const float*)d_in[5];   // (1024,1024)
  const float* opb   = (const float*)d_in[6];   // (1024,)
  float* out = (float*)d_out;
  float* ws  = (float*)d_ws;

  float* XQ = ws + OFF_XQ;
  float* XK = ws + OFF_XK;
  float* XV = ws + OFF_XV;
  float* XO = ws + OFF_XO;
  float* P  = ws + OFF_P;

  dim3 blk(256);

  // in-projections: M=2048 rows
  gemm_nt_bias_k<<<dim3(16, 32), blk, 0, stream>>>(
      query, ipw, ipb, XQ, 1024, 1024, 1024, 1024);
  gemm_nt_bias_k<<<dim3(4, 32), blk, 0, stream>>>(
      key, ipw + (size_t)1024 * 1024, ipb + 1024, XK, 1024, 1024, 1024, 256);
  gemm_nt_bias_k<<<dim3(4, 32), blk, 0, stream>>>(
      value, ipw + (size_t)1280 * 1024, ipb + 1280, XV, 1024, 1024, 1024, 256);

  // scores + sigmoid + clip -> P
  scores_k<<<dim3(16, 16, 32), blk, 0, stream>>>(XQ, XK, P);

  // monotonic recurrence in place (one wave per z)
  mono_rec_k<<<dim3(32), dim3(64), 0, stream>>>(P);

  // phi @ V -> XO
  pv_k<<<dim3(1, 16, 32), blk, 0, stream>>>(P, XV, XO);

  // out-projection
  gemm_nt_bias_k<<<dim3(16, 32), blk, 0, stream>>>(
      XO, opw, opb, out, 1024, 1024, 1024, 1024);
}

// Round 5
// 850.051 us; speedup vs baseline: 1.8805x; 1.2119x over previous
//
#include <hip/hip_runtime.h>
#include <cstddef>
#include <cstdint>

// Problem constants: EMBED=1024, NUM_HEADS=16, GQA=4, KV_HEADS=4,
// HEAD_DIM=64, KV_EMBED=256, EPS=1e-3, B=2, T=1024.
#define TSEQ 1024

typedef __attribute__((ext_vector_type(8))) short short8;   // 8 bf16 = 4 VGPRs
typedef __attribute__((ext_vector_type(4))) float floatx4;  // MFMA acc

// Workspace layout (floats):
//  XQ : 2048 x 1024  (2M)
//  XK : 2048 x 256   (0.5M)
//  XVt: 2 x 256 x 1024 (0.5M)  -- V-projection TRANSPOSED: [b][h*64+c][j]
//  XO : 2048 x 1024  (2M)
//  P  : 32 x 1024x1024 (33.55M) -- probs, overwritten in place by phi
static constexpr size_t OFF_XQ  = 0;
static constexpr size_t OFF_XK  = (size_t)2 * 1024 * 1024;
static constexpr size_t OFF_XVT = OFF_XK + (size_t)512 * 1024;
static constexpr size_t OFF_XO  = OFF_XVT + (size_t)512 * 1024;
static constexpr size_t OFF_P   = OFF_XO + (size_t)2 * 1024 * 1024;

// ---------------------------------------------------------------------------
// fp32 -> bf16 hi/lo split (RNE). x ≈ hi + lo with residual ~2^-17 |x|.
// ---------------------------------------------------------------------------
__device__ __forceinline__ void cvt_hi_lo(float x, unsigned short& hi,
                                          unsigned short& lo) {
  unsigned u = __float_as_uint(x);
  unsigned rh = (u + 0x7FFFu + ((u >> 16) & 1u)) & 0xFFFF0000u;
  hi = (unsigned short)(rh >> 16);
  float xl = x - __uint_as_float(rh);
  unsigned ul = __float_as_uint(xl);
  unsigned rl = ul + 0x7FFFu + ((ul >> 16) & 1u);
  lo = (unsigned short)(rl >> 16);
}

// ---------------------------------------------------------------------------
// Unified NT GEMM core, MFMA bf16x3:  C[M,N] = A[M,K] @ B[N,K]^T (+ epilogue)
// 64x64 tile / block (256 thr, 4 waves), BK=32, v_mfma_f32_16x16x32_bf16.
// Fragment layouts (m89/m91/m120-verified on gfx950):
//   A: lane holds A[m=lane&15][k=quad*8+j]  (8 bf16, ds_read_b128)
//   B: lane holds B[n=lane&15][k=quad*8+j]
//   C/D: col=lane&15, row=quad*4+reg
// bf16x3: acc += Ah*Bh + Ah*Bl + Al*Bh  (al*bl dropped, ~2^-16 rel err).
// LDS rows padded to 40 ushorts (80B): frag-read lanes land 2-way/bank = free.
// EPI: 0 = +bias[col] (bias may be null), 1 = +bias[row], 2 = sigmoid+clip.
// ---------------------------------------------------------------------------
template <int EPI>
__device__ __forceinline__ void mfma_nt_core(
    const float* __restrict__ A, int lda,
    const float* __restrict__ B, int ldb,
    float* __restrict__ C, int ldc, int K,
    const float* __restrict__ bias)
{
  __shared__ __align__(16) unsigned short Ah[64][40];
  __shared__ __align__(16) unsigned short Al[64][40];
  __shared__ __align__(16) unsigned short Bh[64][40];
  __shared__ __align__(16) unsigned short Bl[64][40];

  const int bm = blockIdx.y << 6;
  const int bn = blockIdx.x << 6;
  const int tid  = threadIdx.x;
  const int lane = tid & 63;
  const int wave = tid >> 6;        // 0..3 -> row sub-tile
  const int m16  = lane & 15;
  const int quad = lane >> 4;

  const int srow = tid >> 2;        // staging: row 0..63
  const int skq  = (tid & 3) << 3;  // staging: k offset 0,8,16,24

  floatx4 acc[4];
#pragma unroll
  for (int c = 0; c < 4; ++c) acc[c] = (floatx4){0.f, 0.f, 0.f, 0.f};

  for (int k0 = 0; k0 < K; k0 += 32) {
    // ---- stage A,B 64x32 fp32 tiles as bf16 hi/lo in LDS ----
    {
      const float* ap = A + (size_t)(bm + srow) * lda + (k0 + skq);
      const float* bp = B + (size_t)(bn + srow) * ldb + (k0 + skq);
      float av[8] __attribute__((aligned(16)));
      float bv[8] __attribute__((aligned(16)));
      *(float4*)&av[0] = *(const float4*)(ap);
      *(float4*)&av[4] = *(const float4*)(ap + 4);
      *(float4*)&bv[0] = *(const float4*)(bp);
      *(float4*)&bv[4] = *(const float4*)(bp + 4);
      short8 vah, valo, vbh, vblo;
#pragma unroll
      for (int e = 0; e < 8; ++e) {
        unsigned short h, l;
        cvt_hi_lo(av[e], h, l);
        vah[e] = (short)h; valo[e] = (short)l;
        cvt_hi_lo(bv[e], h, l);
        vbh[e] = (short)h; vblo[e] = (short)l;
      }
      *(short8*)&Ah[srow][skq] = vah;
      *(short8*)&Al[srow][skq] = valo;
      *(short8*)&Bh[srow][skq] = vbh;
      *(short8*)&Bl[srow][skq] = vblo;
    }
    __syncthreads();

    // ---- fragments + MFMA ----
    const int arow = (wave << 4) + m16;
    const short8 a_h = *(const short8*)&Ah[arow][quad << 3];
    const short8 a_l = *(const short8*)&Al[arow][quad << 3];
#pragma unroll
    for (int c = 0; c < 4; ++c) {
      const int brow = (c << 4) + m16;
      const short8 b_h = *(const short8*)&Bh[brow][quad << 3];
      const short8 b_l = *(const short8*)&Bl[brow][quad << 3];
      acc[c] = __builtin_amdgcn_mfma_f32_16x16x32_bf16(a_h, b_h, acc[c], 0, 0, 0);
      acc[c] = __builtin_amdgcn_mfma_f32_16x16x32_bf16(a_h, b_l, acc[c], 0, 0, 0);
      acc[c] = __builtin_amdgcn_mfma_f32_16x16x32_bf16(a_l, b_h, acc[c], 0, 0, 0);
    }
    __syncthreads();
  }

  // ---- epilogue: C/D layout col=lane&15, row=quad*4+reg ----
#pragma unroll
  for (int c = 0; c < 4; ++c) {
#pragma unroll
    for (int r = 0; r < 4; ++r) {
      const int row = (wave << 4) + (quad << 2) + r;
      const int col = (c << 4) + m16;
      float v = acc[c][r];
      if (EPI == 0) { if (bias) v += bias[bn + col]; }
      if (EPI == 1) { v += bias[bm + row]; }
      if (EPI == 2) {
        v = 1.0f / (1.0f + expf(-v));
        v = fminf(fmaxf(v, 0.001f), 0.999f);
      }
      C[(size_t)(bm + row) * ldc + (bn + col)] = v;
    }
  }
}

// ---------------------------------------------------------------------------
// Wrappers
// ---------------------------------------------------------------------------
__global__ __launch_bounds__(256) void gemm_nt_mfma_k(
    const float* __restrict__ A, int lda, const float* __restrict__ W, int ldw,
    const float* __restrict__ bias, float* __restrict__ C, int ldc, int K)
{
  mfma_nt_core<0>(A, lda, W, ldw, C, ldc, K, bias);
}

// V projection, transposed output: XVt[b][c][j] = vw[c,:]·value[b,j,:] + vb[c]
__global__ __launch_bounds__(256) void proj_vt_k(
    const float* __restrict__ vw, const float* __restrict__ value,
    const float* __restrict__ vb, float* __restrict__ XVt)
{
  const int b = blockIdx.z;
  mfma_nt_core<1>(vw, 1024, value + ((size_t)b << 20), 1024,
                  XVt + (size_t)b * 256 * 1024, 1024, 1024, vb);
}

// Scores: per z=(b*16+head): P[z][i][j] = clip(sigmoid(Q_row_i · K_row_j))
__global__ __launch_bounds__(256) void scores_mfma_k(
    const float* __restrict__ XQ, const float* __restrict__ XK,
    float* __restrict__ P)
{
  const int z = blockIdx.z;
  const int b = z >> 4;
  mfma_nt_core<2>(XQ + ((size_t)b << 20) + ((size_t)(z & 15) << 6), 1024,
                  XK + (size_t)b * TSEQ * 256 + ((size_t)(z & 3) << 6), 256,
                  P + ((size_t)z << 20), 1024, 64, nullptr);
}

// PV: XO[b, i, head*64+c] = sum_j phi[z][i][j] * XVt[b][h*64+c][j]  (NT!)
__global__ __launch_bounds__(256) void pv_mfma_k(
    const float* __restrict__ P, const float* __restrict__ XVt,
    float* __restrict__ XO)
{
  const int z = blockIdx.z;
  const int b = z >> 4;
  mfma_nt_core<0>(P + ((size_t)z << 20), 1024,
                  XVt + (size_t)b * 256 * 1024 + (size_t)(z & 3) * 64 * 1024, 1024,
                  XO + ((size_t)b << 20) + ((size_t)(z & 15) << 6), 1024,
                  1024, nullptr);
}

// ---------------------------------------------------------------------------
// Monotonic recurrence, in place over P (probs -> phi).  [R2-PROVEN VERSION —
// do not touch: DPP variants failed twice; this shfl scan is verified.]
// ONE WAVE per z. Lane t owns columns [16t, 16t+16). No barriers.
// ---------------------------------------------------------------------------
__global__ __launch_bounds__(64) void mono_rec_k(float* __restrict__ P)
{
  const int z = blockIdx.x;
  float* __restrict__ Pz = P + ((size_t)z << 20);
  const int t = threadIdx.x;     // lane 0..63
  const int col0 = t << 4;       // first owned column

  float b[16];                   // b_c = phi[i-1,c]*p[i-1,c] for next row
  float p0[16], p1[16], p2[16];  // rotating p-row buffers

  // --- row 0: phi = onehot(0); b = phi0 * p_row0 (only col 0 nonzero) ---
  const float p00 = Pz[0];       // read BEFORE overwriting row 0 in place
  {
    float4 z4 = make_float4(0.f, 0.f, 0.f, 0.f);
    float4 v0 = z4;
    if (t == 0) v0.x = 1.0f;
    *(float4*)(Pz + col0 + 0)  = v0;
    *(float4*)(Pz + col0 + 4)  = z4;
    *(float4*)(Pz + col0 + 8)  = z4;
    *(float4*)(Pz + col0 + 12) = z4;
  }
#pragma unroll
  for (int c = 0; c < 16; ++c) b[c] = 0.0f;
  if (t == 0) b[0] = p00;

  // preload rows 1 and 2
#pragma unroll
  for (int q = 0; q < 4; ++q)
    *(float4*)&p0[4 * q] = *(const float4*)(Pz + ((size_t)1 << 10) + col0 + 4 * q);
#pragma unroll
  for (int q = 0; q < 4; ++q)
    *(float4*)&p1[4 * q] = *(const float4*)(Pz + ((size_t)2 << 10) + col0 + 4 * q);

  auto step = [&](int i, float (&pu)[16], float (&pw)[16]) {
    // prefetch row i+2 (clamped; clamped loads are never consumed)
    const size_t rowpf = (size_t)((i + 2 < TSEQ) ? (i + 2) : (TSEQ - 1)) << 10;
#pragma unroll
    for (int q = 0; q < 4; ++q)
      *(float4*)&pw[4 * q] = *(const float4*)(Pz + rowpf + col0 + 4 * q);

    // A_c = 1 - p[i, c-1]; boundary from left lane; global col 0 -> A = 0
    const float pl = __shfl_up(pu[15], 1);
    const float A0 = (t == 0) ? 0.0f : (1.0f - pl);

    // local inclusive affine prefix over own 16 columns
    float SA[16], SB[16];
    SA[0] = A0;
    SB[0] = b[0];
#pragma unroll
    for (int c = 1; c < 16; ++c) {
      const float Ac = 1.0f - pu[c - 1];
      SA[c] = SA[c - 1] * Ac;
      SB[c] = fmaf(SB[c - 1], Ac, b[c]);
    }

    // wave-wide inclusive scan of lane totals (affine composition)
    float tA = SA[15], tB = SB[15];
#pragma unroll
    for (int off = 1; off < 64; off <<= 1) {
      const float uA = __shfl_up(tA, off);
      const float uB = __shfl_up(tB, off);
      if (t >= off) { tB = fmaf(uB, tA, tB); tA = uA * tA; }
    }
    // exclusive prefix B for this lane
    float pB = __shfl_up(tB, 1);
    if (t == 0) pB = 0.0f;

    // apply, store row i, and build next row's b = phi_new * p_cur
    float phin[16];
#pragma unroll
    for (int c = 0; c < 16; ++c) {
      phin[c] = fmaf(pB, SA[c], SB[c]);
      b[c] = phin[c] * pu[c];
    }
    float* rowp = Pz + ((size_t)i << 10) + col0;
#pragma unroll
    for (int q = 0; q < 4; ++q)
      *(float4*)(rowp + 4 * q) = *(float4*)&phin[4 * q];
  };

  // 1023 iterations = 341 groups of 3; buffer roles rotate (pu, prefetch tgt)
  for (int i = 1; i < TSEQ; i += 3) {
    step(i + 0, p0, p2);
    step(i + 1, p1, p0);
    step(i + 2, p2, p1);
  }
}

// ---------------------------------------------------------------------------
extern "C" void kernel_launch(void* const* d_in, const int* in_sizes, int n_in,
                              void* d_out, int out_size, void* d_ws, size_t ws_size,
                              hipStream_t stream)
{
  const float* query = (const float*)d_in[0];
  const float* key   = (const float*)d_in[1];
  const float* value = (const float*)d_in[2];
  const float* ipw   = (const float*)d_in[3];   // (1536,1024)
  const float* ipb   = (const float*)d_in[4];   // (1536,)
  const float* opw   = (const float*)d_in[5];   // (1024,1024)
  const float* opb   = (const float*)d_in[6];   // (1024,)
  float* out = (float*)d_out;
  float* ws  = (float*)d_ws;

  float* XQ  = ws + OFF_XQ;
  float* XK  = ws + OFF_XK;
  float* XVt = ws + OFF_XVT;
  float* XO  = ws + OFF_XO;
  float* P   = ws + OFF_P;

  // in-projections (MFMA bf16x3)
  gemm_nt_mfma_k<<<dim3(16, 32), 256, 0, stream>>>(
      query, 1024, ipw, 1024, ipb, XQ, 1024, 1024);
  gemm_nt_mfma_k<<<dim3(4, 32), 256, 0, stream>>>(
      key, 1024, ipw + (size_t)1024 * 1024, 1024, ipb + 1024, XK, 256, 1024);
  proj_vt_k<<<dim3(16, 4, 2), 256, 0, stream>>>(
      ipw + (size_t)1280 * 1024, value, ipb + 1280, XVt);

  // scores + sigmoid + clip -> P
  scores_mfma_k<<<dim3(16, 16, 32), 256, 0, stream>>>(XQ, XK, P);

  // monotonic recurrence in place (one wave per z) — R2-proven
  mono_rec_k<<<dim3(32), dim3(64), 0, stream>>>(P);

  // phi @ V -> XO (NT against transposed V)
  pv_mfma_k<<<dim3(1, 16, 32), 256, 0, stream>>>(P, XVt, XO);

  // out-projection
  gemm_nt_mfma_k<<<dim3(16, 32), 256, 0, stream>>>(
      XO, 1024, opw, 1024, opb, out, 1024, 1024);
}

// Round 7
// 796.697 us; speedup vs baseline: 2.0064x; 1.0670x over previous
//
#include <hip/hip_runtime.h>
#include <cstddef>
#include <cstdint>

// Problem constants: EMBED=1024, NUM_HEADS=16, GQA=4, KV_HEADS=4,
// HEAD_DIM=64, KV_EMBED=256, EPS=1e-3, B=2, T=1024.
#define TSEQ 1024

typedef __attribute__((ext_vector_type(8))) short short8;   // 8 bf16 = 4 VGPRs
typedef __attribute__((ext_vector_type(4))) float floatx4;  // MFMA acc

// Workspace layout (floats):
//  XQ : 2048 x 1024  (2M)
//  XK : 2048 x 256   (0.5M)
//  XVt: 2 x 256 x 1024 (0.5M)  -- V-projection TRANSPOSED: [b][h*64+c][j]
//  XO : 2048 x 1024  (2M)
//  P  : 32 x 1024x1024 (33.55M) -- probs, overwritten in place by phi
static constexpr size_t OFF_XQ  = 0;
static constexpr size_t OFF_XK  = (size_t)2 * 1024 * 1024;
static constexpr size_t OFF_XVT = OFF_XK + (size_t)512 * 1024;
static constexpr size_t OFF_XO  = OFF_XVT + (size_t)512 * 1024;
static constexpr size_t OFF_P   = OFF_XO + (size_t)2 * 1024 * 1024;

// ---------------------------------------------------------------------------
// fp32 -> bf16 hi/lo split (RNE). x ≈ hi + lo with residual ~2^-17 |x|.
// ---------------------------------------------------------------------------
__device__ __forceinline__ void cvt_hi_lo(float x, unsigned short& hi,
                                          unsigned short& lo) {
  unsigned u = __float_as_uint(x);
  unsigned rh = (u + 0x7FFFu + ((u >> 16) & 1u)) & 0xFFFF0000u;
  hi = (unsigned short)(rh >> 16);
  float xl = x - __uint_as_float(rh);
  unsigned ul = __float_as_uint(xl);
  unsigned rl = ul + 0x7FFFu + ((ul >> 16) & 1u);
  lo = (unsigned short)(rl >> 16);
}

// ---------------------------------------------------------------------------
// Unified NT GEMM core, MFMA bf16x3 (R5-proven, do not touch).
// ---------------------------------------------------------------------------
template <int EPI>
__device__ __forceinline__ void mfma_nt_core(
    const float* __restrict__ A, int lda,
    const float* __restrict__ B, int ldb,
    float* __restrict__ C, int ldc, int K,
    const float* __restrict__ bias)
{
  __shared__ __align__(16) unsigned short Ah[64][40];
  __shared__ __align__(16) unsigned short Al[64][40];
  __shared__ __align__(16) unsigned short Bh[64][40];
  __shared__ __align__(16) unsigned short Bl[64][40];

  const int bm = blockIdx.y << 6;
  const int bn = blockIdx.x << 6;
  const int tid  = threadIdx.x;
  const int lane = tid & 63;
  const int wave = tid >> 6;        // 0..3 -> row sub-tile
  const int m16  = lane & 15;
  const int quad = lane >> 4;

  const int srow = tid >> 2;        // staging: row 0..63
  const int skq  = (tid & 3) << 3;  // staging: k offset 0,8,16,24

  floatx4 acc[4];
#pragma unroll
  for (int c = 0; c < 4; ++c) acc[c] = (floatx4){0.f, 0.f, 0.f, 0.f};

  for (int k0 = 0; k0 < K; k0 += 32) {
    {
      const float* ap = A + (size_t)(bm + srow) * lda + (k0 + skq);
      const float* bp = B + (size_t)(bn + srow) * ldb + (k0 + skq);
      float av[8] __attribute__((aligned(16)));
      float bv[8] __attribute__((aligned(16)));
      *(float4*)&av[0] = *(const float4*)(ap);
      *(float4*)&av[4] = *(const float4*)(ap + 4);
      *(float4*)&bv[0] = *(const float4*)(bp);
      *(float4*)&bv[4] = *(const float4*)(bp + 4);
      short8 vah, valo, vbh, vblo;
#pragma unroll
      for (int e = 0; e < 8; ++e) {
        unsigned short h, l;
        cvt_hi_lo(av[e], h, l);
        vah[e] = (short)h; valo[e] = (short)l;
        cvt_hi_lo(bv[e], h, l);
        vbh[e] = (short)h; vblo[e] = (short)l;
      }
      *(short8*)&Ah[srow][skq] = vah;
      *(short8*)&Al[srow][skq] = valo;
      *(short8*)&Bh[srow][skq] = vbh;
      *(short8*)&Bl[srow][skq] = vblo;
    }
    __syncthreads();

    const int arow = (wave << 4) + m16;
    const short8 a_h = *(const short8*)&Ah[arow][quad << 3];
    const short8 a_l = *(const short8*)&Al[arow][quad << 3];
#pragma unroll
    for (int c = 0; c < 4; ++c) {
      const int brow = (c << 4) + m16;
      const short8 b_h = *(const short8*)&Bh[brow][quad << 3];
      const short8 b_l = *(const short8*)&Bl[brow][quad << 3];
      acc[c] = __builtin_amdgcn_mfma_f32_16x16x32_bf16(a_h, b_h, acc[c], 0, 0, 0);
      acc[c] = __builtin_amdgcn_mfma_f32_16x16x32_bf16(a_h, b_l, acc[c], 0, 0, 0);
      acc[c] = __builtin_amdgcn_mfma_f32_16x16x32_bf16(a_l, b_h, acc[c], 0, 0, 0);
    }
    __syncthreads();
  }

#pragma unroll
  for (int c = 0; c < 4; ++c) {
#pragma unroll
    for (int r = 0; r < 4; ++r) {
      const int row = (wave << 4) + (quad << 2) + r;
      const int col = (c << 4) + m16;
      float v = acc[c][r];
      if (EPI == 0) { if (bias) v += bias[bn + col]; }
      if (EPI == 1) { v += bias[bm + row]; }
      if (EPI == 2) {
        v = 1.0f / (1.0f + expf(-v));
        v = fminf(fmaxf(v, 0.001f), 0.999f);
      }
      C[(size_t)(bm + row) * ldc + (bn + col)] = v;
    }
  }
}

__global__ __launch_bounds__(256) void gemm_nt_mfma_k(
    const float* __restrict__ A, int lda, const float* __restrict__ W, int ldw,
    const float* __restrict__ bias, float* __restrict__ C, int ldc, int K)
{
  mfma_nt_core<0>(A, lda, W, ldw, C, ldc, K, bias);
}

__global__ __launch_bounds__(256) void proj_vt_k(
    const float* __restrict__ vw, const float* __restrict__ value,
    const float* __restrict__ vb, float* __restrict__ XVt)
{
  const int b = blockIdx.z;
  mfma_nt_core<1>(vw, 1024, value + ((size_t)b << 20), 1024,
                  XVt + (size_t)b * 256 * 1024, 1024, 1024, vb);
}

__global__ __launch_bounds__(256) void scores_mfma_k(
    const float* __restrict__ XQ, const float* __restrict__ XK,
    float* __restrict__ P)
{
  const int z = blockIdx.z;
  const int b = z >> 4;
  mfma_nt_core<2>(XQ + ((size_t)b << 20) + ((size_t)(z & 15) << 6), 1024,
                  XK + (size_t)b * TSEQ * 256 + ((size_t)(z & 3) << 6), 256,
                  P + ((size_t)z << 20), 1024, 64, nullptr);
}

__global__ __launch_bounds__(256) void pv_mfma_k(
    const float* __restrict__ P, const float* __restrict__ XVt,
    float* __restrict__ XO)
{
  const int z = blockIdx.z;
  const int b = z >> 4;
  mfma_nt_core<0>(P + ((size_t)z << 20), 1024,
                  XVt + (size_t)b * 256 * 1024 + (size_t)(z & 3) * 64 * 1024, 1024,
                  XO + ((size_t)b << 20) + ((size_t)(z & 15) << 6), 1024,
                  1024, nullptr);
}

// ---------------------------------------------------------------------------
// Monotonic recurrence, in place over P (probs -> phi). ONE WAVE per z.
// Lane t owns columns [16t,16t+16). Cross-lane = __shfl_up ONLY (R2-proven;
// DPP failed 3x on gfx950 -- permanently banned here).
//
// TWO ROWS PER PASS: state s_j = (phi[i,j], phi[i+1,j]) obeys
//   s_j = M_j s_{j-1} + c_j,  M_j = [[H_j,0],[q_j H_j, G_j]] (lower-tri),
//   H_j = 1-p[i,j-1], G_j = 1-p[i+1,j-1], q_j = p[i,j],
//   c_j = (u_j, q_j u_j), u_j = p[i-1,j]*phi[i-1,j]  (the b[] carry).
// Affine maps tracked as (a, cc, d, bx, by); compose cur∘up:
//   a=a*ua; cc=cc*ua+d*ucc; d=d*ud; bx=a*ubx+bx; by=cc*ubx+d*uby+by.
// Per pass: local 16-col total chain -> 6-stage Kogge-Stone over lane maps
// (5 shfl/stage, one wait) -> exclusive state -> cheap 3-FMA/col re-run to
// apply. 511 passes + 1 single-row step ~ halves the number of scan
// critical paths vs R2. Boundary cols p[*, col0-1] come from memory with the
// pair prefetch (safe vs in-place overwrite: read 2 passes before write).
// ---------------------------------------------------------------------------
__global__ __launch_bounds__(64) void mono_rec_k(float* __restrict__ P)
{
  const int z = blockIdx.x;
  float* __restrict__ Pz = P + ((size_t)z << 20);
  const int t = threadIdx.x;     // lane 0..63
  const int col0 = t << 4;       // first owned column
  const int bofs = (t == 0) ? 0 : (col0 - 1);   // boundary col (dummy at t=0)

  float b[16];                   // u-carry: b_c = phi[i-1,c]*p[i-1,c]

  // --- row 0: phi = onehot(0); b = phi0 * p_row0 (only col 0 nonzero) ---
  const float p00 = Pz[0];       // read BEFORE overwriting row 0 in place
  {
    float4 z4 = make_float4(0.f, 0.f, 0.f, 0.f);
    float4 v0 = z4;
    if (t == 0) v0.x = 1.0f;
    *(float4*)(Pz + col0 + 0)  = v0;
    *(float4*)(Pz + col0 + 4)  = z4;
    *(float4*)(Pz + col0 + 8)  = z4;
    *(float4*)(Pz + col0 + 12) = z4;
  }
#pragma unroll
  for (int c = 0; c < 16; ++c) b[c] = 0.0f;
  if (t == 0) b[0] = p00;

  // --- row 1: single-row step (R2-proven scalar affine scan) ---
  {
    float pu1[16];
#pragma unroll
    for (int q = 0; q < 4; ++q)
      *(float4*)&pu1[4 * q] = *(const float4*)(Pz + ((size_t)1 << 10) + col0 + 4 * q);

    const float pl = __shfl_up(pu1[15], 1);
    const float A0 = (t == 0) ? 0.0f : (1.0f - pl);
    float SA[16], SB[16];
    SA[0] = A0;
    SB[0] = b[0];
#pragma unroll
    for (int c = 1; c < 16; ++c) {
      const float Ac = 1.0f - pu1[c - 1];
      SA[c] = SA[c - 1] * Ac;
      SB[c] = fmaf(SB[c - 1], Ac, b[c]);
    }
    float tA = SA[15], tB = SB[15];
#pragma unroll
    for (int off = 1; off < 64; off <<= 1) {
      const float uA = __shfl_up(tA, off);
      const float uB = __shfl_up(tB, off);
      if (t >= off) { tB = fmaf(uB, tA, tB); tA = uA * tA; }
    }
    float pB = __shfl_up(tB, 1);
    if (t == 0) pB = 0.0f;
    float phin[16];
#pragma unroll
    for (int c = 0; c < 16; ++c) {
      phin[c] = fmaf(pB, SA[c], SB[c]);
      b[c] = phin[c] * pu1[c];
    }
    float* rowp = Pz + ((size_t)1 << 10) + col0;
#pragma unroll
    for (int q = 0; q < 4; ++q)
      *(float4*)(rowp + 4 * q) = *(float4*)&phin[4 * q];
  }

  // --- pair passes: rows (2,3), (4,5), ..., (1022,1023): 511 passes ---
  float cu[16], cv[16], wu[16], wv[16];   // ping-pong pair buffers
  float cqu, cqv, wqu, wqv;               // boundary values p[row, col0-1]

  // preload rows 2,3 + boundaries directly
#pragma unroll
  for (int q = 0; q < 4; ++q) {
    *(float4*)&cu[4 * q] = *(const float4*)(Pz + ((size_t)2 << 10) + col0 + 4 * q);
    *(float4*)&cv[4 * q] = *(const float4*)(Pz + ((size_t)3 << 10) + col0 + 4 * q);
  }
  cqu = Pz[((size_t)2 << 10) + bofs];
  cqv = Pz[((size_t)3 << 10) + bofs];

  auto pass2 = [&](int i, float (&up)[16], float (&vp)[16],
                   const float qu, const float qv,
                   float (&pwu)[16], float (&pwv)[16],
                   float& pqu, float& pqv) {
    // prefetch rows i+2, i+3 (+boundaries); clamped loads never consumed
    const size_t r2 = (size_t)((i + 2 < TSEQ) ? (i + 2) : (TSEQ - 1)) << 10;
    const size_t r3 = (size_t)((i + 3 < TSEQ) ? (i + 3) : (TSEQ - 1)) << 10;
#pragma unroll
    for (int q = 0; q < 4; ++q) {
      *(float4*)&pwu[4 * q] = *(const float4*)(Pz + r2 + col0 + 4 * q);
      *(float4*)&pwv[4 * q] = *(const float4*)(Pz + r3 + col0 + 4 * q);
    }
    pqu = Pz[r2 + bofs];
    pqv = Pz[r3 + bofs];

    // boundary coefficients; global col 0 -> 0
    const float H0 = (t == 0) ? 0.0f : (1.0f - qu);
    const float G0 = (t == 0) ? 0.0f : (1.0f - qv);

    // lane-total affine map (a, cc, d, bx, by) over own 16 columns
    float a = H0, d = G0;
    float bx = b[0];
    float cc = up[0] * a;
    float by = up[0] * bx;
#pragma unroll
    for (int c = 1; c < 16; ++c) {
      const float H  = 1.0f - up[c - 1];
      const float G  = 1.0f - vp[c - 1];
      const float qq = up[c];
      a  = H * a;
      bx = fmaf(H, bx, b[c]);
      cc = fmaf(G, cc, qq * a);    // uses NEW a
      by = fmaf(G, by, qq * bx);   // uses NEW bx
      d  = G * d;
    }

    // 64-lane inclusive Kogge-Stone over lane maps (cur ∘ up)
#pragma unroll
    for (int off = 1; off < 64; off <<= 1) {
      const float ua  = __shfl_up(a, off);
      const float ucc = __shfl_up(cc, off);
      const float ud  = __shfl_up(d, off);
      const float ubx = __shfl_up(bx, off);
      const float uby = __shfl_up(by, off);
      if (t >= off) {
        const float nbx = fmaf(a, ubx, bx);
        const float nby = fmaf(cc, ubx, fmaf(d, uby, by));
        const float ncc = fmaf(cc, ua, d * ucc);
        a = a * ua;
        d = d * ud;
        bx = nbx; by = nby; cc = ncc;
      }
    }

    // exclusive incoming state for this lane (global start state = (0,0))
    float Xx = __shfl_up(bx, 1);
    float Xy = __shfl_up(by, 1);
    if (t == 0) { Xx = 0.0f; Xy = 0.0f; }

    // re-run local recurrence with incoming state; build next b-carry
    float xa[16], ya[16];
    float x = fmaf(H0, Xx, b[0]);
    float y = fmaf(G0, Xy, up[0] * x);
    xa[0] = x; ya[0] = y; b[0] = y * vp[0];
#pragma unroll
    for (int c = 1; c < 16; ++c) {
      x = fmaf(1.0f - up[c - 1], x, b[c]);
      y = fmaf(1.0f - vp[c - 1], y, up[c] * x);
      xa[c] = x; ya[c] = y; b[c] = y * vp[c];
    }
    float* rowu = Pz + ((size_t)i << 10) + col0;
    float* rowv = rowu + TSEQ;
#pragma unroll
    for (int q = 0; q < 4; ++q) {
      *(float4*)(rowu + 4 * q) = *(float4*)&xa[4 * q];
      *(float4*)(rowv + 4 * q) = *(float4*)&ya[4 * q];
    }
  };

  // 255 ping-pong rounds (510 passes, i=2..1020) + final pass i=1022
  int i = 2;
  for (int k = 0; k < 255; ++k) {
    pass2(i, cu, cv, cqu, cqv, wu, wv, wqu, wqv);
    pass2(i + 2, wu, wv, wqu, wqv, cu, cv, cqu, cqv);
    i += 4;
  }
  pass2(1022, cu, cv, cqu, cqv, wu, wv, wqu, wqv);
}

// ---------------------------------------------------------------------------
extern "C" void kernel_launch(void* const* d_in, const int* in_sizes, int n_in,
                              void* d_out, int out_size, void* d_ws, size_t ws_size,
                              hipStream_t stream)
{
  const float* query = (const float*)d_in[0];
  const float* key   = (const float*)d_in[1];
  const float* value = (const float*)d_in[2];
  const float* ipw   = (const float*)d_in[3];   // (1536,1024)
  const float* ipb   = (const float*)d_in[4];   // (1536,)
  const float* opw   = (const float*)d_in[5];   // (1024,1024)
  const float* opb   = (const float*)d_in[6];   // (1024,)
  float* out = (float*)d_out;
  float* ws  = (float*)d_ws;

  float* XQ  = ws + OFF_XQ;
  float* XK  = ws + OFF_XK;
  float* XVt = ws + OFF_XVT;
  float* XO  = ws + OFF_XO;
  float* P   = ws + OFF_P;

  // in-projections (MFMA bf16x3)
  gemm_nt_mfma_k<<<dim3(16, 32), 256, 0, stream>>>(
      query, 1024, ipw, 1024, ipb, XQ, 1024, 1024);
  gemm_nt_mfma_k<<<dim3(4, 32), 256, 0, stream>>>(
      key, 1024, ipw + (size_t)1024 * 1024, 1024, ipb + 1024, XK, 256, 1024);
  proj_vt_k<<<dim3(16, 4, 2), 256, 0, stream>>>(
      ipw + (size_t)1280 * 1024, value, ipb + 1280, XVt);

  // scores + sigmoid + clip -> P
  scores_mfma_k<<<dim3(16, 16, 32), 256, 0, stream>>>(XQ, XK, P);

  // monotonic recurrence in place (one wave per z; 2-row affine-map passes)
  mono_rec_k<<<dim3(32), dim3(64), 0, stream>>>(P);

  // phi @ V -> XO (NT against transposed V)
  pv_mfma_k<<<dim3(1, 16, 32), 256, 0, stream>>>(P, XVt, XO);

  // out-projection
  gemm_nt_mfma_k<<<dim3(16, 32), 256, 0, stream>>>(
      XO, 1024, opw, 1024, opb, out, 1024, 1024);
}